// Round 15
// baseline (161.821 us; speedup 1.0000x reference)
//
#include <hip/hip_runtime.h>

#define N0 4096
#define N1 2048
#define N2 1024

__device__ __forceinline__ void nt_store4(float* p, float4 v) {
    __builtin_nontemporal_store(v.x, p);
    __builtin_nontemporal_store(v.y, p + 1);
    __builtin_nontemporal_store(v.z, p + 2);
    __builtin_nontemporal_store(v.w, p + 3);
}

// ============ restrict: fc = restrict(f + 0.2*L(f)) — R8-proven ============
__global__ __launch_bounds__(256, 4) void k_res_restrict(const float* __restrict__ f,
                                                         float* __restrict__ fc,
                                                         int n, int nc) {
    const int tid = threadIdx.x;
    const int tx = tid & 63, ty = tid >> 6;
    const int fy0 = blockIdx.y * 16, fx0 = blockIdx.x * 256;
    const bool laneL = (tx == 0), laneR = (tx == 63);
    const bool edge = (blockIdx.x == 0) | (blockIdx.y == 0) |
                      (blockIdx.x == gridDim.x - 1) | (blockIdx.y == gridDim.y - 1);

    float4 o4[6]; float os[6];
    #pragma unroll
    for (int rr = 0; rr < 6; ++rr) {
        int gy = max(0, min(n - 1, fy0 + 4 * ty - 1 + rr));
        const float* rowp = f + (size_t)gy * n;
        o4[rr] = *(const float4*)(rowp + fx0 + 4 * tx);
        if (laneL) os[rr] = rowp[max(0, fx0 - 1)];
        if (laneR) os[rr] = rowp[min(n - 1, fx0 + 256)];
    }
    float fa[6][6];
    #pragma unroll
    for (int rr = 0; rr < 6; ++rr) {
        fa[rr][1] = o4[rr].x; fa[rr][2] = o4[rr].y; fa[rr][3] = o4[rr].z; fa[rr][4] = o4[rr].w;
        fa[rr][0] = __shfl_up(o4[rr].w, 1);
        fa[rr][5] = __shfl_down(o4[rr].x, 1);
        if (laneL) fa[rr][0] = os[rr];
        if (laneR) fa[rr][5] = os[rr];
    }
    float rv[4][4];
    #pragma unroll
    for (int i = 0; i < 4; ++i) {
        #pragma unroll
        for (int j = 0; j < 4; ++j) {
            float c = fa[1 + i][1 + j];
            rv[i][j] = c + 0.2f * (fa[i][1 + j] + fa[2 + i][1 + j] +
                                   fa[1 + i][j] + fa[1 + i][2 + j] - 4.0f * c);
        }
    }
    if (edge) {
        #pragma unroll
        for (int i = 0; i < 4; ++i)
            #pragma unroll
            for (int j = 0; j < 4; ++j) {
                int gy = fy0 + 4 * ty + i, gx = fx0 + 4 * tx + j;
                if (gy == 0 || gy == n - 1 || gx == 0 || gx == n - 1)
                    rv[i][j] = fa[1 + i][1 + j];
            }
    }
    #pragma unroll
    for (int da = 0; da < 2; ++da) {
        float2 o;
        o.x = 0.25f * (rv[2*da][0] + rv[2*da][1] + rv[2*da+1][0] + rv[2*da+1][1]);
        o.y = 0.25f * (rv[2*da][2] + rv[2*da][3] + rv[2*da+1][2] + rv[2*da+1][3]);
        *(float2*)(fc + (size_t)(fy0 / 2 + 2 * ty + da) * nc + (fx0 / 2 + 2 * tx)) = o;
    }
}

// ====== fused smooth (persistent grid-stride): u = jacobi(cf*f + cs*prolong(uc), f) ======
// Tile: 256(x) x 16(y); 512 threads = 8 waves x 2 rows; thread = 4 cols x 2 rows.
// Each block loops over tiles bid, bid+grid, ... — waves stay resident, ramp amortized.
template <bool RESID>
__global__ __launch_bounds__(512, 4) void k_smooth_wide(
        const float* __restrict__ f, const float* __restrict__ uc,
        float* __restrict__ u, int n, int m, float cf, float cs,
        double* __restrict__ pT, double* __restrict__ pF, int nTX, int nTY) {
    __shared__ __align__(16) float su[RESID ? 18 : 1][260];
    __shared__ double sred[16];
    const int tid = threadIdx.x;
    const int tx = tid & 63, ty = tid >> 6;           // ty 0..7
    const bool laneL = (tx == 0), laneR = (tx == 63);
    const int nTiles = nTX * nTY;

    for (int bid = blockIdx.x; bid < nTiles; bid += gridDim.x) {
        const int bxi = bid % nTX, byi = bid / nTX;
        const int bx0 = bxi * 256, by0 = byi * 16;
        const int Y  = by0 + 2 * ty;
        const int A0 = by0 >> 1;
        const int A  = A0 + ty;
        const int C  = (bx0 >> 1) + 2 * tx;
        const bool edge = (bxi == 0) | (byi == 0) | (bxi == nTX - 1) | (byi == nTY - 1);

        // ================= phase 1: issue ALL global loads =================
        float4 f4[4]; float fs[4];
        #pragma unroll
        for (int r = 0; r < 4; ++r) {
            int gy = max(0, min(n - 1, Y - 1 + r));
            const float* rowp = f + (size_t)gy * n;
            f4[r] = *(const float4*)(rowp + bx0 + 4 * tx);
            if (laneL) fs[r] = rowp[max(0, bx0 - 1)];
            if (laneR) fs[r] = rowp[min(n - 1, bx0 + 256)];
        }
        float2 c2[3]; float csd[3];
        #pragma unroll
        for (int i = 0; i < 3; ++i) {
            int ga = max(0, min(m - 1, A - 1 + i));
            const float* cp = uc + (size_t)ga * m;
            c2[i] = *(const float2*)(cp + C);
            if (laneL) csd[i] = cp[max(0, C - 1)];
            if (laneR) csd[i] = cp[min(m - 1, C + 2)];
        }
        float4 fH4 = make_float4(0.f, 0.f, 0.f, 0.f); float fHs = 0.f;
        float2 cH2 = make_float2(0.f, 0.f);            float cHs = 0.f;
        float fsd2[2] = {0.f, 0.f}; float csd2[3] = {0.f, 0.f, 0.f};
        if (RESID) {
            if (ty == 0) {
                const float* rowp = f + (size_t)max(0, by0 - 2) * n;
                fH4 = *(const float4*)(rowp + bx0 + 4 * tx);
                if (laneL) fHs = rowp[max(0, bx0 - 1)];
                if (laneR) fHs = rowp[min(n - 1, bx0 + 256)];
                const float* cp = uc + (size_t)max(0, A0 - 2) * m;
                cH2 = *(const float2*)(cp + C);
                if (laneL) cHs = cp[max(0, C - 1)];
                if (laneR) cHs = cp[min(m - 1, C + 2)];
            }
            if (ty == 7) {
                const float* rowp = f + (size_t)min(n - 1, by0 + 17) * n;
                fH4 = *(const float4*)(rowp + bx0 + 4 * tx);
                if (laneL) fHs = rowp[max(0, bx0 - 1)];
                if (laneR) fHs = rowp[min(n - 1, bx0 + 256)];
                const float* cp = uc + (size_t)min(m - 1, A0 + 9) * m;
                cH2 = *(const float2*)(cp + C);
                if (laneL) cHs = cp[max(0, C - 1)];
                if (laneR) cHs = cp[min(m - 1, C + 2)];
            }
            if (laneL) {
                #pragma unroll
                for (int i = 0; i < 3; ++i) {
                    int ga = max(0, min(m - 1, A - 1 + i));
                    csd2[i] = uc[(size_t)ga * m + max(0, C - 2)];
                }
                #pragma unroll
                for (int k = 0; k < 2; ++k)
                    fsd2[k] = f[(size_t)(Y + k) * n + max(0, bx0 - 2)];
            }
            if (laneR) {
                #pragma unroll
                for (int i = 0; i < 3; ++i) {
                    int ga = max(0, min(m - 1, A - 1 + i));
                    csd2[i] = uc[(size_t)ga * m + min(m - 1, C + 3)];
                }
                #pragma unroll
                for (int k = 0; k < 2; ++k)
                    fsd2[k] = f[(size_t)(Y + k) * n + min(n - 1, bx0 + 257)];
            }
        }

        // ================= phase 2: compute =================
        float fr[4][6];
        #pragma unroll
        for (int r = 0; r < 4; ++r) {
            fr[r][1] = f4[r].x; fr[r][2] = f4[r].y; fr[r][3] = f4[r].z; fr[r][4] = f4[r].w;
            fr[r][0] = __shfl_up(f4[r].w, 1);
            fr[r][5] = __shfl_down(f4[r].x, 1);
            if (laneL) fr[r][0] = fs[r];
            if (laneR) fr[r][5] = fs[r];
        }
        float cu[3][4];
        #pragma unroll
        for (int i = 0; i < 3; ++i) {
            float l  = __shfl_up(c2[i].y, 1);
            float rg = __shfl_down(c2[i].x, 1);
            if (laneL) l  = csd[i];
            if (laneR) rg = csd[i];
            cu[i][0] = cs * l; cu[i][1] = cs * c2[i].x; cu[i][2] = cs * c2[i].y; cu[i][3] = cs * rg;
        }
        float h[3][6];
        #pragma unroll
        for (int i = 0; i < 3; ++i) {
            h[i][0] = 1.5f * cu[i][0] + 0.5f * cu[i][1];
            h[i][1] = 0.5f * cu[i][0] + 1.5f * cu[i][1];
            h[i][2] = 1.5f * cu[i][1] + 0.5f * cu[i][2];
            h[i][3] = 0.5f * cu[i][1] + 1.5f * cu[i][2];
            h[i][4] = 1.5f * cu[i][2] + 0.5f * cu[i][3];
            h[i][5] = 0.5f * cu[i][2] + 1.5f * cu[i][3];
        }
        float v[4][6];
        #pragma unroll
        for (int j = 0; j < 6; ++j) {
            v[0][j] = 1.5f * h[0][j] + 0.5f * h[1][j] + cf * fr[0][j];
            v[1][j] = 0.5f * h[0][j] + 1.5f * h[1][j] + cf * fr[1][j];
            v[2][j] = 1.5f * h[1][j] + 0.5f * h[2][j] + cf * fr[2][j];
            v[3][j] = 0.5f * h[1][j] + 1.5f * h[2][j] + cf * fr[3][j];
        }
        if (edge) {
            #pragma unroll
            for (int r = 0; r < 4; ++r)
                #pragma unroll
                for (int j = 0; j < 6; ++j) {
                    int gy = Y - 1 + r, gx = bx0 + 4 * tx - 1 + j;
                    if (gy == 0 || gy == n - 1 || gx == 0 || gx == n - 1) v[r][j] = cf * fr[r][j];
                }
        }
        float u2[2][4];
        #pragma unroll
        for (int rr = 0; rr < 2; ++rr)
            #pragma unroll
            for (int cc = 0; cc < 4; ++cc) {
                float vc = v[1 + rr][1 + cc];
                u2[rr][cc] = vc + cf * fr[1 + rr][1 + cc]
                           + 0.2f * (v[rr][1 + cc] + v[2 + rr][1 + cc] +
                                     v[1 + rr][cc] + v[1 + rr][2 + cc] - 4.0f * vc);
            }
        if (edge) {
            #pragma unroll
            for (int rr = 0; rr < 2; ++rr)
                #pragma unroll
                for (int cc = 0; cc < 4; ++cc) {
                    int gy = Y + rr, gx = bx0 + 4 * tx + cc;
                    if (gy == 0 || gy == n - 1 || gx == 0 || gx == n - 1)
                        u2[rr][cc] = v[1 + rr][1 + cc] + cf * fr[1 + rr][1 + cc];
                }
        }
        #pragma unroll
        for (int rr = 0; rr < 2; ++rr) {
            float4 uu = make_float4(u2[rr][0], u2[rr][1], u2[rr][2], u2[rr][3]);
            float* dst = u + (size_t)(Y + rr) * n + (bx0 + 4 * tx);
            if (RESID) nt_store4(dst, uu);      // u0: streaming output, never re-read
            else       *(float4*)dst = uu;      // u1: re-read by next level
        }

        if (RESID) {
            // ---- halo u rows ----
            if (ty == 0) {
                float l  = __shfl_up(cH2.y, 1);
                float rg = __shfl_down(cH2.x, 1);
                if (laneL) l  = cHs;
                if (laneR) rg = cHs;
                l *= cs; rg *= cs;
                float ox = cs * cH2.x, oy = cs * cH2.y;
                float hm[4] = { 0.5f * l + 1.5f * ox, 1.5f * ox + 0.5f * oy,
                                0.5f * ox + 1.5f * oy, 1.5f * oy + 0.5f * rg };
                float fmv[4] = { fH4.x, fH4.y, fH4.z, fH4.w };
                float vm[4], uHt[4];
                #pragma unroll
                for (int cc = 0; cc < 4; ++cc) vm[cc] = 0.5f * hm[cc] + 1.5f * h[0][1 + cc] + cf * fmv[cc];
                if (edge) {
                    #pragma unroll
                    for (int cc = 0; cc < 4; ++cc) {
                        int gx = bx0 + 4 * tx + cc;
                        if (gx == 0 || gx == n - 1) vm[cc] = cf * fmv[cc];
                    }
                }
                #pragma unroll
                for (int cc = 0; cc < 4; ++cc) {
                    float vc = v[0][1 + cc];
                    uHt[cc] = vc + cf * fr[0][1 + cc]
                            + 0.2f * (vm[cc] + v[1][1 + cc] + v[0][cc] + v[0][2 + cc] - 4.0f * vc);
                }
                if (edge) {
                    #pragma unroll
                    for (int cc = 0; cc < 4; ++cc) {
                        int gx = bx0 + 4 * tx + cc;
                        if (gx == 0 || gx == n - 1) uHt[cc] = v[0][1 + cc] + cf * fr[0][1 + cc];
                    }
                }
                *(float4*)&su[0][4 * tx] = make_float4(uHt[0], uHt[1], uHt[2], uHt[3]);
            }
            if (ty == 7) {
                float l  = __shfl_up(cH2.y, 1);
                float rg = __shfl_down(cH2.x, 1);
                if (laneL) l  = cHs;
                if (laneR) rg = cHs;
                l *= cs; rg *= cs;
                float ox = cs * cH2.x, oy = cs * cH2.y;
                float hp[4] = { 0.5f * l + 1.5f * ox, 1.5f * ox + 0.5f * oy,
                                0.5f * ox + 1.5f * oy, 1.5f * oy + 0.5f * rg };
                float fpv[4] = { fH4.x, fH4.y, fH4.z, fH4.w };
                float vp[4], uHb[4];
                #pragma unroll
                for (int cc = 0; cc < 4; ++cc) vp[cc] = 1.5f * h[2][1 + cc] + 0.5f * hp[cc] + cf * fpv[cc];
                if (edge) {
                    #pragma unroll
                    for (int cc = 0; cc < 4; ++cc) {
                        int gx = bx0 + 4 * tx + cc;
                        if (gx == 0 || gx == n - 1) vp[cc] = cf * fpv[cc];
                    }
                }
                #pragma unroll
                for (int cc = 0; cc < 4; ++cc) {
                    float vc = v[3][1 + cc];
                    uHb[cc] = vc + cf * fr[3][1 + cc]
                            + 0.2f * (v[2][1 + cc] + vp[cc] + v[3][cc] + v[3][2 + cc] - 4.0f * vc);
                }
                if (edge) {
                    #pragma unroll
                    for (int cc = 0; cc < 4; ++cc) {
                        int gx = bx0 + 4 * tx + cc;
                        if (gx == 0 || gx == n - 1) uHb[cc] = v[3][1 + cc] + cf * fr[3][1 + cc];
                    }
                }
                *(float4*)&su[17][4 * tx] = make_float4(uHb[0], uHb[1], uHb[2], uHb[3]);
            }
            // ---- side columns ----
            float uL[2] = {0.f, 0.f}, uR[2] = {0.f, 0.f};
            if (laneL) {
                float hL[3];
                #pragma unroll
                for (int i = 0; i < 3; ++i) hL[i] = 0.5f * cs * csd2[i] + 1.5f * cu[i][0];
                float vL[2] = { 0.5f * hL[0] + 1.5f * hL[1] + cf * fsd2[0],
                                1.5f * hL[1] + 0.5f * hL[2] + cf * fsd2[1] };
                if (edge) {
                    #pragma unroll
                    for (int k = 0; k < 2; ++k) {
                        int gy = Y + k;
                        if (gy == 0 || gy == n - 1) vL[k] = cf * fsd2[k];
                    }
                }
                #pragma unroll
                for (int rr = 0; rr < 2; ++rr) {
                    float vc = v[1 + rr][0];
                    uL[rr] = vc + cf * fr[1 + rr][0]
                           + 0.2f * (v[rr][0] + v[2 + rr][0] + vL[rr] + v[1 + rr][1] - 4.0f * vc);
                    if (edge) {
                        int gy = Y + rr;
                        if (gy == 0 || gy == n - 1) uL[rr] = vc + cf * fr[1 + rr][0];
                    }
                }
            }
            if (laneR) {
                float hR[3];
                #pragma unroll
                for (int i = 0; i < 3; ++i) hR[i] = 1.5f * cu[i][3] + 0.5f * cs * csd2[i];
                float vR[2] = { 0.5f * hR[0] + 1.5f * hR[1] + cf * fsd2[0],
                                1.5f * hR[1] + 0.5f * hR[2] + cf * fsd2[1] };
                if (edge) {
                    #pragma unroll
                    for (int k = 0; k < 2; ++k) {
                        int gy = Y + k;
                        if (gy == 0 || gy == n - 1) vR[k] = cf * fsd2[k];
                    }
                }
                #pragma unroll
                for (int rr = 0; rr < 2; ++rr) {
                    float vc = v[1 + rr][5];
                    uR[rr] = vc + cf * fr[1 + rr][5]
                           + 0.2f * (v[rr][5] + v[2 + rr][5] + v[1 + rr][4] + vR[rr] - 4.0f * vc);
                    if (edge) {
                        int gy = Y + rr;
                        if (gy == 0 || gy == n - 1) uR[rr] = vc + cf * fr[1 + rr][5];
                    }
                }
            }
            // ---- u exchange (one barrier) ----
            #pragma unroll
            for (int rr = 0; rr < 2; ++rr)
                *(float4*)&su[2 * ty + 1 + rr][4 * tx] =
                    make_float4(u2[rr][0], u2[rr][1], u2[rr][2], u2[rr][3]);
            __syncthreads();
            float4 tv = *(const float4*)&su[2 * ty][4 * tx];
            float4 bv = *(const float4*)&su[2 * ty + 3][4 * tx];
            float ta[4] = { tv.x, tv.y, tv.z, tv.w };
            float ba[4] = { bv.x, bv.y, bv.z, bv.w };
            float lft[2], rgt[2];
            lft[0] = __shfl_up(u2[0][3], 1);   lft[1] = __shfl_up(u2[1][3], 1);
            rgt[0] = __shfl_down(u2[0][0], 1); rgt[1] = __shfl_down(u2[1][0], 1);
            if (laneL) { lft[0] = uL[0]; lft[1] = uL[1]; }
            if (laneR) { rgt[0] = uR[0]; rgt[1] = uR[1]; }
            const float n2 = (float)n * (float)n;
            float accT = 0.0f, accF = 0.0f;
            #pragma unroll
            for (int rr = 0; rr < 2; ++rr)
                #pragma unroll
                for (int cc = 0; cc < 4; ++cc) {
                    float up = (rr == 0) ? ta[cc] : u2[0][cc];
                    float dn = (rr == 1) ? ba[cc] : u2[1][cc];
                    float lf = (cc == 0) ? lft[rr] : u2[rr][cc - 1];
                    float rt = (cc == 3) ? rgt[rr] : u2[rr][cc + 1];
                    float uu = u2[rr][cc];
                    float fij = fr[1 + rr][1 + cc];
                    float L = up + dn + lf + rt - 4.0f * uu;
                    float t = fabsf(fij - n2 * L);
                    if (edge) {
                        int gy = Y + rr, gx = bx0 + 4 * tx + cc;
                        if (gy == 0 || gy == n - 1 || gx == 0 || gx == n - 1) t = fabsf(fij);
                    }
                    accT += t;
                    accF += fabsf(fij);
                }
            double vT = (double)accT, vF = (double)accF;
            #pragma unroll
            for (int off = 32; off > 0; off >>= 1) {
                vT += __shfl_down(vT, off);
                vF += __shfl_down(vF, off);
            }
            if (tx == 0) { sred[ty] = vT; sred[8 + ty] = vF; }
            __syncthreads();
            if (tid == 0) {
                double sT = 0.0, sF = 0.0;
                #pragma unroll
                for (int w = 0; w < 8; ++w) { sT += sred[w]; sF += sred[8 + w]; }
                pT[bid] = sT;
                pF[bid] = sF;
            }
            __syncthreads();   // protect su/sred before next iteration overwrites
        }
    }
}

__global__ void k_final(const double* __restrict__ pT, const double* __restrict__ pF,
                        int nb, float* __restrict__ out_res) {
    __shared__ double sT[256], sF[256];
    double tT = 0.0, tF = 0.0;
    for (int i = threadIdx.x; i < nb; i += 256) { tT += pT[i]; tF += pF[i]; }
    sT[threadIdx.x] = tT; sF[threadIdx.x] = tF;
    __syncthreads();
    for (int s = 128; s > 0; s >>= 1) {
        if (threadIdx.x < s) { sT[threadIdx.x] += sT[threadIdx.x + s]; sF[threadIdx.x] += sF[threadIdx.x + s]; }
        __syncthreads();
    }
    if (threadIdx.x == 0) *out_res = (float)(sT[0] / sF[0]);
}

extern "C" void kernel_launch(void* const* d_in, const int* in_sizes, int n_in,
                              void* d_out, int out_size, void* d_ws, size_t ws_size,
                              hipStream_t stream) {
    const float* f0 = (const float*)d_in[0];
    float* u0  = (float*)d_out;
    float* res = u0 + (size_t)N0 * N0;

    char* ws = (char*)d_ws;
    float* f1 = (float*)ws;                                            // N1*N1
    float* u1 = (float*)(ws + (size_t)N1 * N1 * 4);                    // N1*N1
    float* f2 = (float*)(ws + (size_t)2 * N1 * N1 * 4);                // N2*N2
    double* pT = (double*)(ws + (size_t)2 * N1 * N1 * 4 + (size_t)N2 * N2 * 4);
    const int NB = (N0 / 256) * (N0 / 16);                             // 4096 tiles
    double* pF = pT + NB;

    const float c0 = -0.2f / ((float)N0 * (float)N0);
    const float c1 = -0.2f / ((float)N1 * (float)N1);
    const float c2 = -0.2f / ((float)N2 * (float)N2);

    k_res_restrict<<<dim3(N0 / 256, N0 / 16), 256, 0, stream>>>(f0, f1, N0, N1);
    k_res_restrict<<<dim3(N1 / 256, N1 / 16), 256, 0, stream>>>(f1, f2, N1, N2);
    // k3: one tile per block (same behavior as R13)
    k_smooth_wide<false><<<(N1 / 256) * (N1 / 16), 512, 0, stream>>>(
        f1, f2, u1, N1, N2, c1, c2, nullptr, nullptr, N1 / 256, N1 / 16);
    // k4: persistent — 1024 blocks (4/CU), 4 tiles each
    k_smooth_wide<true><<<1024, 512, 0, stream>>>(
        f0, u1, u0, N0, N1, c0, 1.0f, pT, pF, N0 / 256, N0 / 16);
    k_final<<<1, 256, 0, stream>>>(pT, pF, NB, res);
}

// Round 16
// 84.597 us; speedup vs baseline: 1.9129x; 1.9129x over previous
//
#include <hip/hip_runtime.h>

#define N0 4096
#define N1 2048
#define N2 1024

__device__ __forceinline__ void nt_store4(float* p, float4 v) {
    __builtin_nontemporal_store(v.x, p);
    __builtin_nontemporal_store(v.y, p + 1);
    __builtin_nontemporal_store(v.z, p + 2);
    __builtin_nontemporal_store(v.w, p + 3);
}

// ============ restrict: fc = restrict(f + 0.2*L(f)) — R8-proven ============
// Block: 256x16 fine tile, 256 threads = 64 lanes x 4 waves; thread = 4x4 fine = 2x2 coarse.
__global__ __launch_bounds__(256, 4) void k_res_restrict(const float* __restrict__ f,
                                                         float* __restrict__ fc,
                                                         int n, int nc) {
    const int tid = threadIdx.x;
    const int tx = tid & 63, ty = tid >> 6;
    const int fy0 = blockIdx.y * 16, fx0 = blockIdx.x * 256;
    const bool laneL = (tx == 0), laneR = (tx == 63);
    const bool edge = (blockIdx.x == 0) | (blockIdx.y == 0) |
                      (blockIdx.x == gridDim.x - 1) | (blockIdx.y == gridDim.y - 1);

    float4 o4[6]; float os[6];
    #pragma unroll
    for (int rr = 0; rr < 6; ++rr) {
        int gy = max(0, min(n - 1, fy0 + 4 * ty - 1 + rr));
        const float* rowp = f + (size_t)gy * n;
        o4[rr] = *(const float4*)(rowp + fx0 + 4 * tx);
        if (laneL) os[rr] = rowp[max(0, fx0 - 1)];
        if (laneR) os[rr] = rowp[min(n - 1, fx0 + 256)];
    }
    float fa[6][6];
    #pragma unroll
    for (int rr = 0; rr < 6; ++rr) {
        fa[rr][1] = o4[rr].x; fa[rr][2] = o4[rr].y; fa[rr][3] = o4[rr].z; fa[rr][4] = o4[rr].w;
        fa[rr][0] = __shfl_up(o4[rr].w, 1);
        fa[rr][5] = __shfl_down(o4[rr].x, 1);
        if (laneL) fa[rr][0] = os[rr];
        if (laneR) fa[rr][5] = os[rr];
    }
    float rv[4][4];
    #pragma unroll
    for (int i = 0; i < 4; ++i) {
        #pragma unroll
        for (int j = 0; j < 4; ++j) {
            float c = fa[1 + i][1 + j];
            rv[i][j] = c + 0.2f * (fa[i][1 + j] + fa[2 + i][1 + j] +
                                   fa[1 + i][j] + fa[1 + i][2 + j] - 4.0f * c);
        }
    }
    if (edge) {
        #pragma unroll
        for (int i = 0; i < 4; ++i)
            #pragma unroll
            for (int j = 0; j < 4; ++j) {
                int gy = fy0 + 4 * ty + i, gx = fx0 + 4 * tx + j;
                if (gy == 0 || gy == n - 1 || gx == 0 || gx == n - 1)
                    rv[i][j] = fa[1 + i][1 + j];
            }
    }
    #pragma unroll
    for (int da = 0; da < 2; ++da) {
        float2 o;
        o.x = 0.25f * (rv[2*da][0] + rv[2*da][1] + rv[2*da+1][0] + rv[2*da+1][1]);
        o.y = 0.25f * (rv[2*da][2] + rv[2*da][3] + rv[2*da+1][2] + rv[2*da+1][3]);
        *(float2*)(fc + (size_t)(fy0 / 2 + 2 * ty + da) * nc + (fx0 / 2 + 2 * tx)) = o;
    }
}

// ====== fused smooth: u = jacobi(cf*f + cs*prolong(uc), f), optional residual ======
// Block: 256(x) x 16(y) outputs; 512 threads = 8 waves x 2 rows; thread = 4 cols x 2 rows.
// ALL global loads issued in phase 1; one barrier (RESID u-halo exchange) only.
// RESID version streams u out with nontemporal stores (u0 never re-read).
template <bool RESID>
__global__ __launch_bounds__(512, 4) void k_smooth_wide(
        const float* __restrict__ f, const float* __restrict__ uc,
        float* __restrict__ u, int n, int m, float cf, float cs,
        double* __restrict__ pT, double* __restrict__ pF) {
    __shared__ __align__(16) float su[RESID ? 18 : 1][260];  // u rows by0-1..by0+16
    __shared__ double sred[16];
    const int tid = threadIdx.x;
    const int tx = tid & 63, ty = tid >> 6;           // ty 0..7
    const int bx0 = blockIdx.x * 256, by0 = blockIdx.y * 16;
    const int Y  = by0 + 2 * ty;                      // first own row
    const int A0 = by0 >> 1;
    const int A  = A0 + ty;
    const int C  = (bx0 >> 1) + 2 * tx;
    const bool laneL = (tx == 0), laneR = (tx == 63);
    const bool edge = (blockIdx.x == 0) | (blockIdx.y == 0) |
                      (blockIdx.x == gridDim.x - 1) | (blockIdx.y == gridDim.y - 1);

    // ================= phase 1: issue ALL global loads =================
    float4 f4[4]; float fs[4];
    #pragma unroll
    for (int r = 0; r < 4; ++r) {
        int gy = max(0, min(n - 1, Y - 1 + r));
        const float* rowp = f + (size_t)gy * n;
        f4[r] = *(const float4*)(rowp + bx0 + 4 * tx);
        if (laneL) fs[r] = rowp[max(0, bx0 - 1)];
        if (laneR) fs[r] = rowp[min(n - 1, bx0 + 256)];
    }
    float2 c2[3]; float csd[3];
    #pragma unroll
    for (int i = 0; i < 3; ++i) {
        int ga = max(0, min(m - 1, A - 1 + i));
        const float* cp = uc + (size_t)ga * m;
        c2[i] = *(const float2*)(cp + C);
        if (laneL) csd[i] = cp[max(0, C - 1)];
        if (laneR) csd[i] = cp[min(m - 1, C + 2)];
    }
    float4 fH4 = make_float4(0.f, 0.f, 0.f, 0.f); float fHs = 0.f;
    float2 cH2 = make_float2(0.f, 0.f);            float cHs = 0.f;
    float fsd2[2] = {0.f, 0.f}; float csd2[3] = {0.f, 0.f, 0.f};
    if (RESID) {
        if (ty == 0) {
            const float* rowp = f + (size_t)max(0, by0 - 2) * n;
            fH4 = *(const float4*)(rowp + bx0 + 4 * tx);
            if (laneL) fHs = rowp[max(0, bx0 - 1)];
            if (laneR) fHs = rowp[min(n - 1, bx0 + 256)];
            const float* cp = uc + (size_t)max(0, A0 - 2) * m;
            cH2 = *(const float2*)(cp + C);
            if (laneL) cHs = cp[max(0, C - 1)];
            if (laneR) cHs = cp[min(m - 1, C + 2)];
        }
        if (ty == 7) {
            const float* rowp = f + (size_t)min(n - 1, by0 + 17) * n;
            fH4 = *(const float4*)(rowp + bx0 + 4 * tx);
            if (laneL) fHs = rowp[max(0, bx0 - 1)];
            if (laneR) fHs = rowp[min(n - 1, bx0 + 256)];
            const float* cp = uc + (size_t)min(m - 1, A0 + 9) * m;
            cH2 = *(const float2*)(cp + C);
            if (laneL) cHs = cp[max(0, C - 1)];
            if (laneR) cHs = cp[min(m - 1, C + 2)];
        }
        if (laneL) {
            #pragma unroll
            for (int i = 0; i < 3; ++i) {
                int ga = max(0, min(m - 1, A - 1 + i));
                csd2[i] = uc[(size_t)ga * m + max(0, C - 2)];
            }
            #pragma unroll
            for (int k = 0; k < 2; ++k)
                fsd2[k] = f[(size_t)(Y + k) * n + max(0, bx0 - 2)];
        }
        if (laneR) {
            #pragma unroll
            for (int i = 0; i < 3; ++i) {
                int ga = max(0, min(m - 1, A - 1 + i));
                csd2[i] = uc[(size_t)ga * m + min(m - 1, C + 3)];
            }
            #pragma unroll
            for (int k = 0; k < 2; ++k)
                fsd2[k] = f[(size_t)(Y + k) * n + min(n - 1, bx0 + 257)];
        }
    }

    // ================= phase 2: compute =================
    float fr[4][6];
    #pragma unroll
    for (int r = 0; r < 4; ++r) {
        fr[r][1] = f4[r].x; fr[r][2] = f4[r].y; fr[r][3] = f4[r].z; fr[r][4] = f4[r].w;
        fr[r][0] = __shfl_up(f4[r].w, 1);
        fr[r][5] = __shfl_down(f4[r].x, 1);
        if (laneL) fr[r][0] = fs[r];
        if (laneR) fr[r][5] = fs[r];
    }
    float cu[3][4];
    #pragma unroll
    for (int i = 0; i < 3; ++i) {
        float l  = __shfl_up(c2[i].y, 1);
        float rg = __shfl_down(c2[i].x, 1);
        if (laneL) l  = csd[i];
        if (laneR) rg = csd[i];
        cu[i][0] = cs * l; cu[i][1] = cs * c2[i].x; cu[i][2] = cs * c2[i].y; cu[i][3] = cs * rg;
    }
    float h[3][6];
    #pragma unroll
    for (int i = 0; i < 3; ++i) {
        h[i][0] = 1.5f * cu[i][0] + 0.5f * cu[i][1];
        h[i][1] = 0.5f * cu[i][0] + 1.5f * cu[i][1];
        h[i][2] = 1.5f * cu[i][1] + 0.5f * cu[i][2];
        h[i][3] = 0.5f * cu[i][1] + 1.5f * cu[i][2];
        h[i][4] = 1.5f * cu[i][2] + 0.5f * cu[i][3];
        h[i][5] = 0.5f * cu[i][2] + 1.5f * cu[i][3];
    }
    float v[4][6];
    #pragma unroll
    for (int j = 0; j < 6; ++j) {
        v[0][j] = 1.5f * h[0][j] + 0.5f * h[1][j] + cf * fr[0][j];
        v[1][j] = 0.5f * h[0][j] + 1.5f * h[1][j] + cf * fr[1][j];
        v[2][j] = 1.5f * h[1][j] + 0.5f * h[2][j] + cf * fr[2][j];
        v[3][j] = 0.5f * h[1][j] + 1.5f * h[2][j] + cf * fr[3][j];
    }
    if (edge) {
        #pragma unroll
        for (int r = 0; r < 4; ++r)
            #pragma unroll
            for (int j = 0; j < 6; ++j) {
                int gy = Y - 1 + r, gx = bx0 + 4 * tx - 1 + j;
                if (gy == 0 || gy == n - 1 || gx == 0 || gx == n - 1) v[r][j] = cf * fr[r][j];
            }
    }
    float u2[2][4];
    #pragma unroll
    for (int rr = 0; rr < 2; ++rr)
        #pragma unroll
        for (int cc = 0; cc < 4; ++cc) {
            float vc = v[1 + rr][1 + cc];
            u2[rr][cc] = vc + cf * fr[1 + rr][1 + cc]
                       + 0.2f * (v[rr][1 + cc] + v[2 + rr][1 + cc] +
                                 v[1 + rr][cc] + v[1 + rr][2 + cc] - 4.0f * vc);
        }
    if (edge) {
        #pragma unroll
        for (int rr = 0; rr < 2; ++rr)
            #pragma unroll
            for (int cc = 0; cc < 4; ++cc) {
                int gy = Y + rr, gx = bx0 + 4 * tx + cc;
                if (gy == 0 || gy == n - 1 || gx == 0 || gx == n - 1)
                    u2[rr][cc] = v[1 + rr][1 + cc] + cf * fr[1 + rr][1 + cc];
            }
    }
    #pragma unroll
    for (int rr = 0; rr < 2; ++rr) {
        float4 uu = make_float4(u2[rr][0], u2[rr][1], u2[rr][2], u2[rr][3]);
        float* dst = u + (size_t)(Y + rr) * n + (bx0 + 4 * tx);
        if (RESID) nt_store4(dst, uu);      // u0: streaming output, never re-read
        else       *(float4*)dst = uu;      // u1: re-read by next level
    }

    if (RESID) {
        // ---- halo u rows (preloaded data, no new global loads) ----
        if (ty == 0) {
            float l  = __shfl_up(cH2.y, 1);
            float rg = __shfl_down(cH2.x, 1);
            if (laneL) l  = cHs;
            if (laneR) rg = cHs;
            l *= cs; rg *= cs;
            float ox = cs * cH2.x, oy = cs * cH2.y;
            float hm[4] = { 0.5f * l + 1.5f * ox, 1.5f * ox + 0.5f * oy,
                            0.5f * ox + 1.5f * oy, 1.5f * oy + 0.5f * rg };
            float fmv[4] = { fH4.x, fH4.y, fH4.z, fH4.w };
            float vm[4], uHt[4];
            #pragma unroll
            for (int cc = 0; cc < 4; ++cc) vm[cc] = 0.5f * hm[cc] + 1.5f * h[0][1 + cc] + cf * fmv[cc];
            if (edge) {
                #pragma unroll
                for (int cc = 0; cc < 4; ++cc) {
                    int gx = bx0 + 4 * tx + cc;
                    if (gx == 0 || gx == n - 1) vm[cc] = cf * fmv[cc];
                }
            }
            #pragma unroll
            for (int cc = 0; cc < 4; ++cc) {
                float vc = v[0][1 + cc];
                uHt[cc] = vc + cf * fr[0][1 + cc]
                        + 0.2f * (vm[cc] + v[1][1 + cc] + v[0][cc] + v[0][2 + cc] - 4.0f * vc);
            }
            if (edge) {
                #pragma unroll
                for (int cc = 0; cc < 4; ++cc) {
                    int gx = bx0 + 4 * tx + cc;
                    if (gx == 0 || gx == n - 1) uHt[cc] = v[0][1 + cc] + cf * fr[0][1 + cc];
                }
            }
            *(float4*)&su[0][4 * tx] = make_float4(uHt[0], uHt[1], uHt[2], uHt[3]);
        }
        if (ty == 7) {
            float l  = __shfl_up(cH2.y, 1);
            float rg = __shfl_down(cH2.x, 1);
            if (laneL) l  = cHs;
            if (laneR) rg = cHs;
            l *= cs; rg *= cs;
            float ox = cs * cH2.x, oy = cs * cH2.y;
            float hp[4] = { 0.5f * l + 1.5f * ox, 1.5f * ox + 0.5f * oy,
                            0.5f * ox + 1.5f * oy, 1.5f * oy + 0.5f * rg };
            float fpv[4] = { fH4.x, fH4.y, fH4.z, fH4.w };
            float vp[4], uHb[4];
            #pragma unroll
            for (int cc = 0; cc < 4; ++cc) vp[cc] = 1.5f * h[2][1 + cc] + 0.5f * hp[cc] + cf * fpv[cc];
            if (edge) {
                #pragma unroll
                for (int cc = 0; cc < 4; ++cc) {
                    int gx = bx0 + 4 * tx + cc;
                    if (gx == 0 || gx == n - 1) vp[cc] = cf * fpv[cc];
                }
            }
            #pragma unroll
            for (int cc = 0; cc < 4; ++cc) {
                float vc = v[3][1 + cc];
                uHb[cc] = vc + cf * fr[3][1 + cc]
                        + 0.2f * (v[2][1 + cc] + vp[cc] + v[3][cc] + v[3][2 + cc] - 4.0f * vc);
            }
            if (edge) {
                #pragma unroll
                for (int cc = 0; cc < 4; ++cc) {
                    int gx = bx0 + 4 * tx + cc;
                    if (gx == 0 || gx == n - 1) uHb[cc] = v[3][1 + cc] + cf * fr[3][1 + cc];
                }
            }
            *(float4*)&su[17][4 * tx] = make_float4(uHb[0], uHb[1], uHb[2], uHb[3]);
        }
        // ---- side columns ----
        float uL[2] = {0.f, 0.f}, uR[2] = {0.f, 0.f};
        if (laneL) {
            float hL[3];
            #pragma unroll
            for (int i = 0; i < 3; ++i) hL[i] = 0.5f * cs * csd2[i] + 1.5f * cu[i][0];
            float vL[2] = { 0.5f * hL[0] + 1.5f * hL[1] + cf * fsd2[0],
                            1.5f * hL[1] + 0.5f * hL[2] + cf * fsd2[1] };
            if (edge) {
                #pragma unroll
                for (int k = 0; k < 2; ++k) {
                    int gy = Y + k;
                    if (gy == 0 || gy == n - 1) vL[k] = cf * fsd2[k];
                }
            }
            #pragma unroll
            for (int rr = 0; rr < 2; ++rr) {
                float vc = v[1 + rr][0];
                uL[rr] = vc + cf * fr[1 + rr][0]
                       + 0.2f * (v[rr][0] + v[2 + rr][0] + vL[rr] + v[1 + rr][1] - 4.0f * vc);
                if (edge) {
                    int gy = Y + rr;
                    if (gy == 0 || gy == n - 1) uL[rr] = vc + cf * fr[1 + rr][0];
                }
            }
        }
        if (laneR) {
            float hR[3];
            #pragma unroll
            for (int i = 0; i < 3; ++i) hR[i] = 1.5f * cu[i][3] + 0.5f * cs * csd2[i];
            float vR[2] = { 0.5f * hR[0] + 1.5f * hR[1] + cf * fsd2[0],
                            1.5f * hR[1] + 0.5f * hR[2] + cf * fsd2[1] };
            if (edge) {
                #pragma unroll
                for (int k = 0; k < 2; ++k) {
                    int gy = Y + k;
                    if (gy == 0 || gy == n - 1) vR[k] = cf * fsd2[k];
                }
            }
            #pragma unroll
            for (int rr = 0; rr < 2; ++rr) {
                float vc = v[1 + rr][5];
                uR[rr] = vc + cf * fr[1 + rr][5]
                       + 0.2f * (v[rr][5] + v[2 + rr][5] + v[1 + rr][4] + vR[rr] - 4.0f * vc);
                if (edge) {
                    int gy = Y + rr;
                    if (gy == 0 || gy == n - 1) uR[rr] = vc + cf * fr[1 + rr][5];
                }
            }
        }
        // ---- u exchange (one barrier) ----
        #pragma unroll
        for (int rr = 0; rr < 2; ++rr)
            *(float4*)&su[2 * ty + 1 + rr][4 * tx] =
                make_float4(u2[rr][0], u2[rr][1], u2[rr][2], u2[rr][3]);
        __syncthreads();
        float4 tv = *(const float4*)&su[2 * ty][4 * tx];
        float4 bv = *(const float4*)&su[2 * ty + 3][4 * tx];
        float ta[4] = { tv.x, tv.y, tv.z, tv.w };
        float ba[4] = { bv.x, bv.y, bv.z, bv.w };
        float lft[2], rgt[2];
        lft[0] = __shfl_up(u2[0][3], 1);   lft[1] = __shfl_up(u2[1][3], 1);
        rgt[0] = __shfl_down(u2[0][0], 1); rgt[1] = __shfl_down(u2[1][0], 1);
        if (laneL) { lft[0] = uL[0]; lft[1] = uL[1]; }
        if (laneR) { rgt[0] = uR[0]; rgt[1] = uR[1]; }
        const float n2 = (float)n * (float)n;
        float accT = 0.0f, accF = 0.0f;
        #pragma unroll
        for (int rr = 0; rr < 2; ++rr)
            #pragma unroll
            for (int cc = 0; cc < 4; ++cc) {
                float up = (rr == 0) ? ta[cc] : u2[0][cc];
                float dn = (rr == 1) ? ba[cc] : u2[1][cc];
                float lf = (cc == 0) ? lft[rr] : u2[rr][cc - 1];
                float rt = (cc == 3) ? rgt[rr] : u2[rr][cc + 1];
                float uu = u2[rr][cc];
                float fij = fr[1 + rr][1 + cc];
                float L = up + dn + lf + rt - 4.0f * uu;
                float t = fabsf(fij - n2 * L);
                if (edge) {
                    int gy = Y + rr, gx = bx0 + 4 * tx + cc;
                    if (gy == 0 || gy == n - 1 || gx == 0 || gx == n - 1) t = fabsf(fij);
                }
                accT += t;
                accF += fabsf(fij);
            }
        double vT = (double)accT, vF = (double)accF;
        #pragma unroll
        for (int off = 32; off > 0; off >>= 1) {
            vT += __shfl_down(vT, off);
            vF += __shfl_down(vF, off);
        }
        if (tx == 0) { sred[ty] = vT; sred[8 + ty] = vF; }
        __syncthreads();
        if (tid == 0) {
            double sT = 0.0, sF = 0.0;
            #pragma unroll
            for (int w = 0; w < 8; ++w) { sT += sred[w]; sF += sred[8 + w]; }
            int bid = blockIdx.y * gridDim.x + blockIdx.x;
            pT[bid] = sT;
            pF[bid] = sF;
        }
    }
}

__global__ void k_final(const double* __restrict__ pT, const double* __restrict__ pF,
                        int nb, float* __restrict__ out_res) {
    __shared__ double sT[256], sF[256];
    double tT = 0.0, tF = 0.0;
    for (int i = threadIdx.x; i < nb; i += 256) { tT += pT[i]; tF += pF[i]; }
    sT[threadIdx.x] = tT; sF[threadIdx.x] = tF;
    __syncthreads();
    for (int s = 128; s > 0; s >>= 1) {
        if (threadIdx.x < s) { sT[threadIdx.x] += sT[threadIdx.x + s]; sF[threadIdx.x] += sF[threadIdx.x + s]; }
        __syncthreads();
    }
    if (threadIdx.x == 0) *out_res = (float)(sT[0] / sF[0]);
}

extern "C" void kernel_launch(void* const* d_in, const int* in_sizes, int n_in,
                              void* d_out, int out_size, void* d_ws, size_t ws_size,
                              hipStream_t stream) {
    const float* f0 = (const float*)d_in[0];
    float* u0  = (float*)d_out;
    float* res = u0 + (size_t)N0 * N0;

    char* ws = (char*)d_ws;
    float* f1 = (float*)ws;                                            // N1*N1
    float* u1 = (float*)(ws + (size_t)N1 * N1 * 4);                    // N1*N1
    float* f2 = (float*)(ws + (size_t)2 * N1 * N1 * 4);                // N2*N2
    double* pT = (double*)(ws + (size_t)2 * N1 * N1 * 4 + (size_t)N2 * N2 * 4);
    const int NB = (N0 / 256) * (N0 / 16);                             // 4096 blocks
    double* pF = pT + NB;

    const float c0 = -0.2f / ((float)N0 * (float)N0);
    const float c1 = -0.2f / ((float)N1 * (float)N1);
    const float c2 = -0.2f / ((float)N2 * (float)N2);

    k_res_restrict<<<dim3(N0 / 256, N0 / 16), 256, 0, stream>>>(f0, f1, N0, N1);
    k_res_restrict<<<dim3(N1 / 256, N1 / 16), 256, 0, stream>>>(f1, f2, N1, N2);
    k_smooth_wide<false><<<dim3(N1 / 256, N1 / 16), 512, 0, stream>>>(
        f1, f2, u1, N1, N2, c1, c2, nullptr, nullptr);
    k_smooth_wide<true><<<dim3(N0 / 256, N0 / 16), 512, 0, stream>>>(
        f0, u1, u0, N0, N1, c0, 1.0f, pT, pF);
    k_final<<<1, 256, 0, stream>>>(pT, pF, NB, res);
}